// Round 3
// baseline (48.337 us; speedup 1.0000x reference)
//
#include <hip/hip_runtime.h>
#include <math.h>

#define NB 64
#define NL 512
#define NC 768
#define NP 196
#define MAXM 32      // slot cap (m observed ~1-3)
#define SCH 4        // LDS tpe slots per chunk
#define RT 4         // blocks per batch
#define ROWS 49      // rows per block (RT*ROWS == NP)
#define NBLK (NB*RT) // 256 blocks total
#define KMAX 7       // max rows per wave: ceil(ROWS/8)

// One fused kernel. Each block: labels (redundant, deterministic) -> tpe in
// LDS -> stream its 49 ipe rows (row-LSE) -> batch-last block does col-LSE
// from gmat -> global-last block reduces partial[] to the scalar.
__global__ __launch_bounds__(512) void fused_kernel(
    const float* __restrict__ text, const float* __restrict__ ipe,
    const int* __restrict__ bbox, const int* __restrict__ attn,
    float* __restrict__ gmat, float* __restrict__ partial,
    int* __restrict__ batch_done, int* __restrict__ done_ctr,
    float* __restrict__ out)
{
  __shared__ __align__(16) float tpl[SCH][NC];
  __shared__ int cnt_s[NP];
  __shared__ int slot_s[NP];
  __shared__ int dlist_s[MAXM];
  __shared__ short vl_s[NL];
  __shared__ short vslot_s[NL];
  __shared__ int wcnt_s[8], vcnt_s[8];
  __shared__ float wsum[8];
  __shared__ int flagA_s;   // last block of this batch
  __shared__ int flagB_s;   // last block overall (separate flag: no reuse race)

  const int b = blockIdx.x, rt = blockIdx.y;
  const int tid = threadIdx.x, wv = tid >> 6, lane = tid & 63;
  const unsigned long long lmask = (1ull << lane) - 1ull;

  // ---- phase 1: per-token label ----
  int lab;
  {
    int4 bb = ((const int4*)bbox)[b * NL + tid];
    int x0 = bb.x / 72, y0 = bb.y / 72, x1 = bb.z / 72, y1 = bb.w / 72;
    lab = (x0 == x1 && y0 == y1) ? (y0 * 14 + x0) : -1;
    if (attn[b * NL + tid] == 0) lab = -1;
  }
  if (tid < NP) { cnt_s[tid] = 0; slot_s[tid] = -1; }
  __syncthreads();
  if (lab >= 0) atomicAdd(&cnt_s[lab], 1);
  __syncthreads();

  // ---- phase 2: DETERMINISTIC slot compaction (identical across the 4
  // blocks of a batch — required since they share gmat slot indexing) ----
  {
    int flagv = (tid < NP && cnt_s[tid] > 0) ? 1 : 0;
    unsigned long long bal = __ballot(flagv);
    int pos = __popcll(bal & lmask);
    if (lane == 0) wcnt_s[wv] = __popcll(bal);
    __syncthreads();
    if (flagv) {
      int off = 0;
      for (int w = 0; w < wv; ++w) off += wcnt_s[w];
      int s = off + pos;
      if (s < MAXM) { slot_s[tid] = s; dlist_s[s] = tid; }
    }
  }
  __syncthreads();
  int m = wcnt_s[0] + wcnt_s[1] + wcnt_s[2] + wcnt_s[3];
  m = min(m, MAXM);

  // deterministic valid-token list (ballot prefix over token index)
  {
    int vflag = (lab >= 0 && slot_s[lab] >= 0) ? 1 : 0;
    unsigned long long bal = __ballot(vflag);
    int pos = __popcll(bal & lmask);
    if (lane == 0) vcnt_s[wv] = __popcll(bal);
    __syncthreads();
    if (vflag) {
      int off = 0;
      for (int w = 0; w < wv; ++w) off += vcnt_s[w];
      int t = off + pos;
      vl_s[t] = (short)tid; vslot_s[t] = (short)slot_s[lab];
    }
  }
  int nv = 0;
  for (int w = 0; w < 8; ++w) nv += vcnt_s[w];
  __syncthreads();

  // ---- phases 3+4: per-chunk tpe build in LDS, then row dots + online LSE --
  float rm[KMAX], rs[KMAX], rd[KMAX];
#pragma unroll
  for (int k = 0; k < KMAX; ++k) { rm[k] = 0.f; rs[k] = (float)(NP - m); rd[k] = 0.f; }

  const int p0 = rt * ROWS;

  for (int s0 = 0; s0 < m; s0 += SCH) {
    const int sc = min(SCH, m - s0);
    __syncthreads();   // previous chunk's readers done before tpl overwrite
    for (int i = tid; i < SCH * NC; i += 512) ((float*)tpl)[i] = 0.f;
    __syncthreads();
    // threads own columns: all RMW chains thread-local, no syncs inside
    for (int t = 0; t < nv; ++t) {
      int s = (int)vslot_s[t] - s0;
      if (s >= 0 && s < sc) {
        const float* tr = text + ((size_t)b * NL + vl_s[t]) * NC;
        for (int c = tid; c < NC; c += 512) tpl[s][c] += tr[c];
      }
    }
    for (int s = 0; s < sc; ++s) {
      float inv = 1.0f / (float)max(cnt_s[dlist_s[s0 + s]], 1);
      for (int c = tid; c < NC; c += 512) tpl[s][c] *= inv;
    }
    __syncthreads();

#pragma unroll
    for (int k = 0; k < KMAX; ++k) {
      const int j = wv + 8 * k;
      if (j < ROWS) {
        const int p = p0 + j;
        const float* ir = ipe + ((size_t)b * NP + p) * NC;
        float acc[SCH];
#pragma unroll
        for (int s = 0; s < SCH; ++s) acc[s] = 0.f;
#pragma unroll
        for (int kk = 0; kk < 3; ++kk) {
          const int c = kk * 256 + lane * 4;
          float4 x = *(const float4*)(ir + c);
#pragma unroll
          for (int s = 0; s < SCH; ++s) {
            if (s < sc) {
              float4 tv = *(const float4*)(&tpl[s][c]);
              acc[s] += x.x * tv.x + x.y * tv.y + x.z * tv.z + x.w * tv.w;
            }
          }
        }
#pragma unroll
        for (int s = 0; s < SCH; ++s) {
          if (s < sc) {
            float v = acc[s];
            for (int off = 32; off > 0; off >>= 1) v += __shfl_xor(v, off, 64);
            acc[s] = v;   // all lanes hold the total
          }
        }
        if (lane == 0) {
#pragma unroll
          for (int s = 0; s < SCH; ++s)
            if (s < sc) gmat[((size_t)b * MAXM + s0 + s) * NP + p] = acc[s];
        }
        float cmax = rm[k];
#pragma unroll
        for (int s = 0; s < SCH; ++s) if (s < sc) cmax = fmaxf(cmax, acc[s]);
        float sum = rs[k] * expf(rm[k] - cmax);
#pragma unroll
        for (int s = 0; s < SCH; ++s) if (s < sc) sum += expf(acc[s] - cmax);
        rm[k] = cmax; rs[k] = sum;
#pragma unroll
        for (int s = 0; s < SCH; ++s)
          if (s < sc && dlist_s[s0 + s] == p) rd[k] = acc[s];
      }
    }
  }

  // ---- row partial for this block ----
  float wacc = 0.f;   // identical across lanes of the wave
#pragma unroll
  for (int k = 0; k < KMAX; ++k) {
    int j = wv + 8 * k;
    if (j < ROWS) wacc += rm[k] + logf(rs[k]) - rd[k];
  }
  if (lane == 0) wsum[wv] = wacc;
  __syncthreads();
  if (tid == 0) {
    float s = wsum[0] + wsum[1] + wsum[2] + wsum[3] +
              wsum[4] + wsum[5] + wsum[6] + wsum[7];
    atomicAdd(&partial[b], s);
    __threadfence();                      // release gmat + partial
    int prev = atomicAdd(&batch_done[b], 1);
    flagA_s = (prev == RT - 1) ? 1 : 0;
  }
  __syncthreads();

  // ---- batch-last block: column LSE over the m valid columns ----
  if (flagA_s) {
    __threadfence();                      // acquire
    float cacc = 0.f;
    for (int s = wv; s < m; s += 8) {
      float* gc = gmat + ((size_t)b * MAXM + s) * NP;
      // atomic RMW reads: coherent across XCD L2s
      float g0 = atomicAdd(&gc[lane], 0.f);
      float g1 = atomicAdd(&gc[lane + 64], 0.f);
      float g2 = atomicAdd(&gc[lane + 128], 0.f);
      float g3 = (lane < NP - 192) ? atomicAdd(&gc[lane + 192], 0.f) : -1e30f;
      float mx = fmaxf(fmaxf(g0, g1), fmaxf(g2, g3));
      for (int off = 32; off > 0; off >>= 1) mx = fmaxf(mx, __shfl_xor(mx, off, 64));
      float se = expf(g0 - mx) + expf(g1 - mx) + expf(g2 - mx) +
                 ((lane < NP - 192) ? expf(g3 - mx) : 0.f);
      for (int off = 32; off > 0; off >>= 1) se += __shfl_xor(se, off, 64);
      if (lane == 0) cacc += (mx + logf(se)) - atomicAdd(&gc[dlist_s[s]], 0.f);
    }
    if (lane == 0) wsum[wv] = cacc;
    __syncthreads();                      // block-uniform branch: safe
    if (tid == 0) {
      float cs = wsum[0] + wsum[1] + wsum[2] + wsum[3] +
                 wsum[4] + wsum[5] + wsum[6] + wsum[7] +
                 (float)(NP - m) * logf((float)NP);
      atomicAdd(&partial[b], cs);
    }
  }

  // ---- global-last block: final reduce ----
  if (tid == 0) {
    __threadfence();                      // release partial
    int prev = atomicAdd(done_ctr, 1);
    flagB_s = (prev == NBLK - 1) ? 1 : 0;
  }
  __syncthreads();
  if (flagB_s) {
    __threadfence();                      // acquire
    if (tid < 64) {
      float v = atomicAdd(&partial[tid], 0.f);
      for (int off = 32; off > 0; off >>= 1) v += __shfl_xor(v, off, 64);
      if (tid == 0) out[0] = v / (float)(2 * NB * NP);
    }
  }
}

extern "C" void kernel_launch(void* const* d_in, const int* in_sizes, int n_in,
                              void* d_out, int out_size, void* d_ws, size_t ws_size,
                              hipStream_t stream) {
  const float* text = (const float*)d_in[0];
  const float* ipe  = (const float*)d_in[1];
  const int*   bbox = (const int*)d_in[2];
  const int*   attn = (const int*)d_in[3];

  float* gmat       = (float*)d_ws;                    // NB*MAXM*NP floats
  float* partial    = gmat + (size_t)NB * MAXM * NP;   // NB floats
  int*   batch_done = (int*)(partial + NB);            // NB ints
  int*   done_c     = batch_done + NB;                 // 1 int

  // zero the 516B counter region (partial + batch_done + done_ctr)
  hipMemsetAsync(partial, 0, (size_t)(NB + NB + 1) * 4, stream);

  dim3 grid(NB, RT);
  fused_kernel<<<grid, 512, 0, stream>>>(text, ipe, bbox, attn, gmat, partial,
                                         batch_done, done_c, (float*)d_out);
}

// Round 4
// 44.028 us; speedup vs baseline: 1.0979x; 1.0979x over previous
//
#include <hip/hip_runtime.h>
#include <math.h>

#define NB 64
#define NL 512
#define NC 768
#define NP 196
#define MAXM 32      // max distinct valid labels per batch (expected ~1-3)
#define RT 7         // k2 blocks per batch
#define RPB 28       // rows per k2 block (RT*RPB == NP)
#define RPW 7        // rows per wave (4 waves * RPW == RPB)
#define SCH 2        // tpe slots per LDS chunk (m<=2 covers ~all batches)

// ---------------------------------------------------------------------------
// Kernel 1 (round-2 proven): per-batch labels, counts, compaction, sparse tpe
// in global. One block per batch, 512 threads. Also zeroes the k2 counters.
// ---------------------------------------------------------------------------
__global__ __launch_bounds__(512) void k1_labels(
    const float* __restrict__ text, const int* __restrict__ bbox,
    const int* __restrict__ attn, float* __restrict__ tpe,
    float* __restrict__ partial, int* __restrict__ m_g, int* __restrict__ dlist_g,
    int* __restrict__ batch_done, int* __restrict__ done_ctr)
{
  __shared__ int cnt_s[NP];
  __shared__ int slot_s[NP];
  __shared__ int dlist_s[MAXM];
  __shared__ short vl_s[NL];
  __shared__ short vslot_s[NL];
  __shared__ int m_s, nv_s;

  const int b = blockIdx.x, tid = threadIdx.x;

  int lab;
  {
    int4 bb = ((const int4*)bbox)[b * NL + tid];
    int x0 = bb.x / 72, y0 = bb.y / 72, x1 = bb.z / 72, y1 = bb.w / 72;
    lab = (x0 == x1 && y0 == y1) ? (y0 * 14 + x0) : -1;
    if (attn[b * NL + tid] == 0) lab = -1;
  }
  if (tid < NP) { cnt_s[tid] = 0; slot_s[tid] = -1; }
  if (tid == 0) {
    m_s = 0; nv_s = 0;
    partial[b] = 0.0f;
    batch_done[b] = 0;
    if (b == 0) *done_ctr = 0;   // visible to k2 via kernel-boundary coherence
  }
  __syncthreads();
  if (lab >= 0) atomicAdd(&cnt_s[lab], 1);
  __syncthreads();
  if (tid < NP && cnt_s[tid] > 0) {
    int s = atomicAdd(&m_s, 1);
    if (s < MAXM) { slot_s[tid] = s; dlist_s[s] = tid; }
  }
  __syncthreads();
  if (lab >= 0) {
    int s = slot_s[lab];
    if (s >= 0) { int t = atomicAdd(&nv_s, 1); vl_s[t] = (short)tid; vslot_s[t] = (short)s; }
  }
  __syncthreads();
  const int m = min(m_s, MAXM), nv = nv_s;
  if (tid == 0) m_g[b] = m;
  if (tid < m) dlist_g[b * MAXM + tid] = dlist_s[tid];

  // Thread owns columns c = tid, tid+512: all RMW chains thread-local.
  float* tpb = tpe + (size_t)b * MAXM * NC;
  for (int s = 0; s < m; ++s)
    for (int c = tid; c < NC; c += 512) tpb[s * NC + c] = 0.0f;
  for (int t = 0; t < nv; ++t) {
    int l = vl_s[t], s = vslot_s[t];
    const float* tr = text + ((size_t)b * NL + l) * NC;
    for (int c = tid; c < NC; c += 512) tpb[s * NC + c] += tr[c];
  }
  for (int s = 0; s < m; ++s) {
    float inv = 1.0f / (float)max(cnt_s[dlist_s[s]], 1);
    for (int c = tid; c < NC; c += 512) tpb[s * NC + c] *= inv;
  }
}

// ---------------------------------------------------------------------------
// Kernel 2: stream ipe rows once; per row compute g_s = <ipe_row, tpe_s>;
// online row-LSE (rm,rs) AND online column (cM,cS) per slot; diag enters as
// -2*rd (row CE and col CE subtract the same g[diag]). Batch-last block
// merges RT column (M,S) pairs per slot; global-last block emits the scalar.
// Grid (NB, RT), 256 threads (4 waves x 7 rows).
// ---------------------------------------------------------------------------
__global__ __launch_bounds__(256) void k2_rows(
    const float* __restrict__ ipe, const float* __restrict__ tpe,
    const int* __restrict__ m_g, const int* __restrict__ dlist_g,
    float* __restrict__ blkstats, float* __restrict__ partial,
    int* __restrict__ batch_done, int* __restrict__ done_ctr,
    float* __restrict__ out)
{
  __shared__ __align__(16) float tpl[SCH][NC];
  __shared__ int dl[SCH];
  __shared__ float wsum[4];
  __shared__ float wcM[4][SCH], wcS[4][SCH];
  __shared__ int flagA_s, flagB_s;

  const int b = blockIdx.x, rt = blockIdx.y, tid = threadIdx.x;
  const int wv = tid >> 6, lane = tid & 63;
  const int m = m_g[b];

  float rm[RPW], rs[RPW], rd[RPW];
#pragma unroll
  for (int r = 0; r < RPW; ++r) {
    rm[r] = 0.0f; rs[r] = (float)(NP - m); rd[r] = 0.0f;
  }

  const int p0 = rt * RPB + wv * RPW;

  for (int s0 = 0; s0 < m; s0 += SCH) {
    const int sc = min(SCH, m - s0);
    __syncthreads();   // previous chunk's tpl/wcM readers done
    for (int s = 0; s < sc; ++s) {
      const float4* src = (const float4*)(tpe + ((size_t)b * MAXM + s0 + s) * NC);
      if (tid < NC / 4) ((float4*)&tpl[s][0])[tid] = src[tid];
    }
    if (tid < SCH) dl[tid] = (tid < sc) ? dlist_g[b * MAXM + s0 + tid] : -2;
    __syncthreads();

    float cM[SCH], cS[SCH];
#pragma unroll
    for (int s = 0; s < SCH; ++s) { cM[s] = -1e30f; cS[s] = 0.0f; }

#pragma unroll
    for (int r = 0; r < RPW; ++r) {
      const int p = p0 + r;
      const float* ir = ipe + ((size_t)b * NP + p) * NC;
      float acc[SCH];
#pragma unroll
      for (int s = 0; s < SCH; ++s) acc[s] = 0.0f;
#pragma unroll
      for (int kk = 0; kk < 3; ++kk) {
        const int c = kk * 256 + lane * 4;
        float4 x = *(const float4*)(ir + c);
#pragma unroll
        for (int s = 0; s < SCH; ++s) {
          if (s < sc) {
            float4 t = *(const float4*)(&tpl[s][c]);
            acc[s] += x.x * t.x + x.y * t.y + x.z * t.z + x.w * t.w;
          }
        }
      }
#pragma unroll
      for (int s = 0; s < SCH; ++s) {
        if (s < sc) {
          float v = acc[s];
          for (int off = 32; off > 0; off >>= 1) v += __shfl_xor(v, off, 64);
          acc[s] = v;   // all lanes hold the total
        }
      }
      // row-side online LSE
      float cmax = rm[r];
#pragma unroll
      for (int s = 0; s < SCH; ++s) if (s < sc) cmax = fmaxf(cmax, acc[s]);
      float sum = rs[r] * expf(rm[r] - cmax);
#pragma unroll
      for (int s = 0; s < SCH; ++s) if (s < sc) sum += expf(acc[s] - cmax);
      rm[r] = cmax; rs[r] = sum;
#pragma unroll
      for (int s = 0; s < SCH; ++s)
        if (s < sc && dl[s] == p) rd[r] = acc[s];
      // col-side online (M,S), uniform across lanes
#pragma unroll
      for (int s = 0; s < SCH; ++s) {
        if (s < sc) {
          float M2 = fmaxf(cM[s], acc[s]);
          cS[s] = cS[s] * expf(cM[s] - M2) + expf(acc[s] - M2);
          cM[s] = M2;
        }
      }
    }

    // merge 4 waves' column stats for this chunk, write blkstats
    if (lane == 0) {
#pragma unroll
      for (int s = 0; s < SCH; ++s) { wcM[wv][s] = cM[s]; wcS[wv][s] = cS[s]; }
    }
    __syncthreads();
    if (tid < sc) {
      float M = wcM[0][tid], S;
      M = fmaxf(M, wcM[1][tid]); M = fmaxf(M, wcM[2][tid]); M = fmaxf(M, wcM[3][tid]);
      S = wcS[0][tid] * expf(wcM[0][tid] - M) + wcS[1][tid] * expf(wcM[1][tid] - M) +
          wcS[2][tid] * expf(wcM[2][tid] - M) + wcS[3][tid] * expf(wcM[3][tid] - M);
      size_t idx = ((size_t)(b * RT + rt) * MAXM + s0 + tid) * 2;
      blkstats[idx + 0] = M;
      blkstats[idx + 1] = S;
    }
  }

  // ---- row partial: sum over this block's 28 rows of (rm + log rs - 2*rd) --
  float wacc = 0.0f;   // identical across lanes of the wave
#pragma unroll
  for (int r = 0; r < RPW; ++r)
    wacc += rm[r] + logf(rs[r]) - 2.0f * rd[r];
  if (lane == 0) wsum[wv] = wacc;
  __syncthreads();
  if (tid == 0) {
    float s = wsum[0] + wsum[1] + wsum[2] + wsum[3];
    atomicAdd(&partial[b], s);
    __threadfence();                       // release blkstats + partial
    int prev = atomicAdd(&batch_done[b], 1);
    flagA_s = (prev == RT - 1) ? 1 : 0;
  }
  __syncthreads();

  // ---- batch-last block: merge RT column (M,S) pairs per slot ----
  if (flagA_s) {
    __threadfence();                       // acquire
    if (wv == 0) {
      float v = 0.0f;
      if (lane < m) {
        float M = -1e30f, S = 0.0f;
        for (int r2 = 0; r2 < RT; ++r2) {
          size_t idx = ((size_t)(b * RT + r2) * MAXM + lane) * 2;
          // atomic RMW reads: coherent across XCD L2s
          float Mr = atomicAdd(&blkstats[idx + 0], 0.0f);
          float Sr = atomicAdd(&blkstats[idx + 1], 0.0f);
          float M2 = fmaxf(M, Mr);
          S = S * expf(M - M2) + Sr * expf(Mr - M2);
          M = M2;
        }
        v = M + logf(S);
      }
      for (int off = 32; off > 0; off >>= 1) v += __shfl_xor(v, off, 64);
      if (lane == 0)
        atomicAdd(&partial[b], v + (float)(NP - m) * logf((float)NP));
    }
  }

  // ---- global-last block: final reduce ----
  if (tid == 0) {
    __threadfence();                       // release partial
    int prev = atomicAdd(done_ctr, 1);
    flagB_s = (prev == NB * RT - 1) ? 1 : 0;
  }
  __syncthreads();
  if (flagB_s) {
    __threadfence();                       // acquire
    if (tid < 64) {
      float v = atomicAdd(&partial[tid], 0.0f);
      for (int off = 32; off > 0; off >>= 1) v += __shfl_xor(v, off, 64);
      if (tid == 0) out[0] = v / (float)(2 * NB * NP);
    }
  }
}

extern "C" void kernel_launch(void* const* d_in, const int* in_sizes, int n_in,
                              void* d_out, int out_size, void* d_ws, size_t ws_size,
                              hipStream_t stream) {
  const float* text = (const float*)d_in[0];
  const float* ipe  = (const float*)d_in[1];
  const int*   bbox = (const int*)d_in[2];
  const int*   attn = (const int*)d_in[3];

  float* tpe        = (float*)d_ws;                        // NB*MAXM*NC
  float* blkstats   = tpe + (size_t)NB * MAXM * NC;        // NB*RT*MAXM*2
  float* partial    = blkstats + (size_t)NB * RT * MAXM * 2; // NB
  int*   m_g        = (int*)(partial + NB);                // NB
  int*   dlist_g    = m_g + NB;                            // NB*MAXM
  int*   batch_done = dlist_g + NB * MAXM;                 // NB
  int*   done_c     = batch_done + NB;                     // 1

  k1_labels<<<NB, 512, 0, stream>>>(text, bbox, attn, tpe, partial, m_g,
                                    dlist_g, batch_done, done_c);
  dim3 g2(NB, RT);
  k2_rows<<<g2, 256, 0, stream>>>(ipe, tpe, m_g, dlist_g, blkstats, partial,
                                  batch_done, done_c, (float*)d_out);
}

// Round 5
// 39.292 us; speedup vs baseline: 1.2302x; 1.1205x over previous
//
#include <hip/hip_runtime.h>
#include <math.h>

#define NB 64
#define NL 512
#define NC 768
#define NP 196
#define MAXM 32        // max distinct valid labels per batch (expected ~1-3)
#define RT 7           // k2 blocks per batch
#define RPB 28         // rows per k2 block (RT*RPB == NP)
#define RPW 7          // rows per wave (4 waves * RPW == RPB)
#define SCH 2          // tpe slots per register chunk (m<=2 covers ~all)
#define NW 4           // waves per k2 block
#define NSTAT (RT*NW)  // 28 col-stat (M,S) pairs per (batch,slot)

// ---------------------------------------------------------------------------
// Kernel 1 (round-2 proven): per-batch labels, counts, compaction, sparse tpe
// in global. One block per batch, 512 threads. Zeroes partial[].
// ---------------------------------------------------------------------------
__global__ __launch_bounds__(512) void k1_labels(
    const float* __restrict__ text, const int* __restrict__ bbox,
    const int* __restrict__ attn, float* __restrict__ tpe,
    float* __restrict__ partial, int* __restrict__ m_g, int* __restrict__ dlist_g)
{
  __shared__ int cnt_s[NP];
  __shared__ int slot_s[NP];
  __shared__ int dlist_s[MAXM];
  __shared__ short vl_s[NL];
  __shared__ short vslot_s[NL];
  __shared__ int m_s, nv_s;

  const int b = blockIdx.x, tid = threadIdx.x;

  int lab;
  {
    int4 bb = ((const int4*)bbox)[b * NL + tid];
    int x0 = bb.x / 72, y0 = bb.y / 72, x1 = bb.z / 72, y1 = bb.w / 72;
    lab = (x0 == x1 && y0 == y1) ? (y0 * 14 + x0) : -1;
    if (attn[b * NL + tid] == 0) lab = -1;
  }
  if (tid < NP) { cnt_s[tid] = 0; slot_s[tid] = -1; }
  if (tid == 0) { m_s = 0; nv_s = 0; partial[b] = 0.0f; }
  __syncthreads();
  if (lab >= 0) atomicAdd(&cnt_s[lab], 1);
  __syncthreads();
  if (tid < NP && cnt_s[tid] > 0) {
    int s = atomicAdd(&m_s, 1);
    if (s < MAXM) { slot_s[tid] = s; dlist_s[s] = tid; }
  }
  __syncthreads();
  if (lab >= 0) {
    int s = slot_s[lab];
    if (s >= 0) { int t = atomicAdd(&nv_s, 1); vl_s[t] = (short)tid; vslot_s[t] = (short)s; }
  }
  __syncthreads();
  const int m = min(m_s, MAXM), nv = nv_s;
  if (tid == 0) m_g[b] = m;
  if (tid < m) dlist_g[b * MAXM + tid] = dlist_s[tid];

  // Thread owns columns c = tid, tid+512: all RMW chains thread-local.
  float* tpb = tpe + (size_t)b * MAXM * NC;
  for (int s = 0; s < m; ++s)
    for (int c = tid; c < NC; c += 512) tpb[s * NC + c] = 0.0f;
  for (int t = 0; t < nv; ++t) {
    int l = vl_s[t], s = vslot_s[t];
    const float* tr = text + ((size_t)b * NL + l) * NC;
    for (int c = tid; c < NC; c += 512) tpb[s * NC + c] += tr[c];
  }
  for (int s = 0; s < m; ++s) {
    float inv = 1.0f / (float)max(cnt_s[dlist_s[s]], 1);
    for (int c = tid; c < NC; c += 512) tpb[s * NC + c] *= inv;
  }
}

// ---------------------------------------------------------------------------
// Kernel 2: stream ipe rows once. tpe fragments live in REGISTERS (each lane
// needs only its 12 floats per slot, reused across 7 rows) — no LDS, no
// __syncthreads, no fences. Row-LSE online with the -2*rd diagonal trick;
// per-wave column (M,S) stats stored plain (merged next kernel). m=0 batches
// contribute analytically and skip the stream. Grid (NB, RT), 256 threads.
// ---------------------------------------------------------------------------
__global__ __launch_bounds__(256) void k2_rows(
    const float* __restrict__ ipe, const float* __restrict__ tpe,
    const int* __restrict__ m_g, const int* __restrict__ dlist_g,
    float* __restrict__ blkstats, float* __restrict__ partial)
{
  const int b = blockIdx.x, rt = blockIdx.y, tid = threadIdx.x;
  const int wv = tid >> 6, lane = tid & 63;
  const int m = m_g[b];

  if (m == 0) {   // rows contribute log(NP) each; no gmat, no col stats
    if (tid == 0) atomicAdd(&partial[b], (float)RPB * logf((float)NP));
    return;
  }

  const int p0 = rt * RPB + wv * RPW;
  const int w = rt * NW + wv;

  float rm[RPW], rs[RPW], rd[RPW];
#pragma unroll
  for (int r = 0; r < RPW; ++r) {
    rm[r] = 0.0f; rs[r] = (float)(NP - m); rd[r] = 0.0f;
  }

  for (int s0 = 0; s0 < m; s0 += SCH) {
    const int sc = min(SCH, m - s0);
    float4 tf[SCH][3];
    int dls[SCH];
#pragma unroll
    for (int s = 0; s < SCH; ++s) {
      if (s < sc) {
        const float* tr = tpe + ((size_t)b * MAXM + s0 + s) * NC;
#pragma unroll
        for (int kk = 0; kk < 3; ++kk)
          tf[s][kk] = *(const float4*)(tr + kk * 256 + lane * 4);
        dls[s] = dlist_g[b * MAXM + s0 + s];
      } else dls[s] = -2;
    }
    float cM[SCH], cS[SCH];
#pragma unroll
    for (int s = 0; s < SCH; ++s) { cM[s] = -1e30f; cS[s] = 0.0f; }

#pragma unroll
    for (int r = 0; r < RPW; ++r) {
      const int p = p0 + r;
      const float* ir = ipe + ((size_t)b * NP + p) * NC;
      float acc[SCH];
#pragma unroll
      for (int s = 0; s < SCH; ++s) acc[s] = 0.0f;
#pragma unroll
      for (int kk = 0; kk < 3; ++kk) {
        float4 x = *(const float4*)(ir + kk * 256 + lane * 4);
#pragma unroll
        for (int s = 0; s < SCH; ++s)
          if (s < sc)
            acc[s] += x.x * tf[s][kk].x + x.y * tf[s][kk].y +
                      x.z * tf[s][kk].z + x.w * tf[s][kk].w;
      }
#pragma unroll
      for (int s = 0; s < SCH; ++s) {
        if (s < sc) {
          float v = acc[s];
          for (int off = 32; off > 0; off >>= 1) v += __shfl_xor(v, off, 64);
          acc[s] = v;   // all lanes hold the total
        }
      }
      // row-side online LSE
      float cmax = rm[r];
#pragma unroll
      for (int s = 0; s < SCH; ++s) if (s < sc) cmax = fmaxf(cmax, acc[s]);
      float sum = rs[r] * expf(rm[r] - cmax);
#pragma unroll
      for (int s = 0; s < SCH; ++s) if (s < sc) sum += expf(acc[s] - cmax);
      rm[r] = cmax; rs[r] = sum;
#pragma unroll
      for (int s = 0; s < SCH; ++s)
        if (s < sc && dls[s] == p) rd[r] = acc[s];
      // col-side online (M,S), uniform across lanes
#pragma unroll
      for (int s = 0; s < SCH; ++s) {
        if (s < sc) {
          float M2 = fmaxf(cM[s], acc[s]);
          cS[s] = cS[s] * expf(cM[s] - M2) + expf(acc[s] - M2);
          cM[s] = M2;
        }
      }
    }
    if (lane == 0) {
#pragma unroll
      for (int s = 0; s < SCH; ++s) {
        if (s < sc) {
          size_t idx = (((size_t)b * NSTAT + w) * MAXM + s0 + s) * 2;
          blkstats[idx] = cM[s]; blkstats[idx + 1] = cS[s];
        }
      }
    }
  }

  // row partial: rows CE + (col diag enters as the second rd)
  float wacc = 0.0f;   // identical across lanes of the wave
#pragma unroll
  for (int r = 0; r < RPW; ++r)
    wacc += rm[r] + logf(rs[r]) - 2.0f * rd[r];
  if (lane == 0) atomicAdd(&partial[b], wacc);
}

// ---------------------------------------------------------------------------
// Kernel 3: one wave; lane b merges its batch's 28 col (M,S) pairs per slot,
// adds the (NP-m)*log(NP) invalid-column term, butterfly-reduces, writes out.
// All inputs written by prior kernels — kernel-boundary coherence, no fences.
// ---------------------------------------------------------------------------
__global__ __launch_bounds__(64) void k3_final(
    const int* __restrict__ m_g, const float* __restrict__ blkstats,
    const float* __restrict__ partial, float* __restrict__ out)
{
  const int b = threadIdx.x;   // 64 lanes == 64 batches
  const int m = m_g[b];
  float tot = partial[b] + (float)(NP - m) * logf((float)NP);
  for (int s = 0; s < m; ++s) {
    float M = -1e30f, S = 0.0f;
    for (int w = 0; w < NSTAT; ++w) {
      size_t idx = (((size_t)b * NSTAT + w) * MAXM + s) * 2;
      float Mr = blkstats[idx], Sr = blkstats[idx + 1];
      float M2 = fmaxf(M, Mr);
      S = S * expf(M - M2) + Sr * expf(Mr - M2);
      M = M2;
    }
    tot += M + logf(S);
  }
  for (int off = 32; off > 0; off >>= 1) tot += __shfl_xor(tot, off, 64);
  if (b == 0) out[0] = tot / (float)(2 * NB * NP);
}

extern "C" void kernel_launch(void* const* d_in, const int* in_sizes, int n_in,
                              void* d_out, int out_size, void* d_ws, size_t ws_size,
                              hipStream_t stream) {
  const float* text = (const float*)d_in[0];
  const float* ipe  = (const float*)d_in[1];
  const int*   bbox = (const int*)d_in[2];
  const int*   attn = (const int*)d_in[3];

  float* tpe      = (float*)d_ws;                          // NB*MAXM*NC
  float* blkstats = tpe + (size_t)NB * MAXM * NC;          // NB*NSTAT*MAXM*2
  float* partial  = blkstats + (size_t)NB * NSTAT * MAXM * 2; // NB
  int*   m_g      = (int*)(partial + NB);                  // NB
  int*   dlist_g  = m_g + NB;                              // NB*MAXM

  k1_labels<<<NB, 512, 0, stream>>>(text, bbox, attn, tpe, partial, m_g, dlist_g);
  dim3 g2(NB, RT);
  k2_rows<<<g2, 256, 0, stream>>>(ipe, tpe, m_g, dlist_g, blkstats, partial);
  k3_final<<<1, 64, 0, stream>>>(m_g, blkstats, partial, (float*)d_out);
}